// Round 1
// baseline (81633.490 us; speedup 1.0000x reference)
//
#include <hip/hip_runtime.h>

typedef float f4 __attribute__((ext_vector_type(4)));
typedef float f2 __attribute__((ext_vector_type(2)));

namespace kfc {
constexpr int TN = 1024;   // time steps
constexpr int NS = 64;     // state dim
constexpr int NO = 32;     // obs dim
constexpr int NI = 16;     // input dim

// ---- LDS layout (floats) ----
constexpr int OFF_AT  = 0;                  // [64x64] A^T   At[k*64+i] = A[i][k]
constexpr int OFF_CT  = OFF_AT  + NS*NS;    // [64x32] C^T   Ct[k*32+r] = C[r][k]
constexpr int OFF_RCT = OFF_CT  + NS*NO;    // [64x32] (Rinv C)^T  RCt[k*32+q]
constexpr int OFF_BT  = OFF_RCT + NS*NO;    // [16x64] B^T   Bt[m*64+i] = B[i][m]
constexpr int OFF_PIM = OFF_BT  + NI*NS;    // [64x64] Pi (stage covariance)
constexpr int OFF_M   = OFF_PIM + NS*NS;    // [64x64] M = K@G
constexpr int OFF_G   = OFF_M   + NS*NS;    // [32x64] G = C@Pi   (init: Rinv scratch)
constexpr int OFF_RG  = OFF_G   + NO*NS;    // [32x64] RG = RinvC@Pi (init: GJ Aug)
constexpr int OFF_AP  = OFF_RG  + NO*NS;    // [64x65] AP = A@Pi, row-padded +1
constexpr int OFF_XV  = OFF_AP  + NS*65;    // [64] stage state xi
constexpr int OFF_UV  = OFF_XV + NS;        // [16] interp u
constexpr int OFF_YV  = OFF_UV + NI;        // [32] interp y
constexpr int OFF_CX  = OFF_YV + NO;        // [32] C@xi
constexpr int OFF_FAC = OFF_CX + NO;        // [32] GJ factors
constexpr int LDS_FLOATS = OFF_FAC + NO;    // 25840 floats = 103360 B

// Dopri5 tableau (stage 7 skipped: b6 = 0, FSAL slope unused)
constexpr float ATAB[6][5] = {
  {0.f,0.f,0.f,0.f,0.f},
  {(float)(1.0/5.0),0.f,0.f,0.f,0.f},
  {(float)(3.0/40.0),(float)(9.0/40.0),0.f,0.f,0.f},
  {(float)(44.0/45.0),(float)(-56.0/15.0),(float)(32.0/9.0),0.f,0.f},
  {(float)(19372.0/6561.0),(float)(-25360.0/2187.0),(float)(64448.0/6561.0),(float)(-212.0/729.0),0.f},
  {(float)(9017.0/3168.0),(float)(-355.0/33.0),(float)(46732.0/5247.0),(float)(49.0/176.0),(float)(-5103.0/18656.0)},
};
constexpr float CTAB[6] = {0.f,(float)(1.0/5.0),(float)(3.0/10.0),(float)(4.0/5.0),(float)(8.0/9.0),1.f};
constexpr float BW0=(float)(35.0/384.0), BW2=(float)(500.0/1113.0), BW3=(float)(125.0/192.0),
                BW4=(float)(-2187.0/6784.0), BW5=(float)(11.0/84.0);
} // namespace kfc

using namespace kfc;

__global__ __launch_bounds__(256, 1)
void kf_kernel(const float* __restrict__ ts, const float* __restrict__ ys,
               const float* __restrict__ us, const float* __restrict__ Ag,
               const float* __restrict__ Bg, const float* __restrict__ Cg,
               const float* __restrict__ x0g, const float* __restrict__ P0g,
               const float* __restrict__ Qg, const float* __restrict__ Rg,
               float* __restrict__ out)
{
  extern __shared__ float lds[];
  const int tid  = (int)threadIdx.x;
  const int w    = tid >> 6;     // wave id 0..3
  const int lane = tid & 63;

  // ================= init: transposed constants =================
  for (int idx = tid; idx < NS*NS; idx += 256) { int i = idx >> 6, k = idx & 63; lds[OFF_AT + k*NS + i] = Ag[idx]; }
  for (int idx = tid; idx < NO*NS; idx += 256) { int r = idx >> 6, k = idx & 63; lds[OFF_CT + k*NO + r] = Cg[idx]; }
  for (int idx = tid; idx < NS*NI; idx += 256) { int i = idx >> 4, m = idx & 15; lds[OFF_BT + m*NS + i] = Bg[idx]; }
  // Gauss-Jordan augmented [R | I] in RG buffer (32x64)
  for (int idx = tid; idx < NO*64; idx += 256) {
    int r = idx >> 6, c = idx & 63;
    lds[OFF_RG + idx] = (c < NO) ? Rg[r*NO + c] : ((c - NO) == r ? 1.f : 0.f);
  }
  __syncthreads();
  // R is SPD & (for this problem) diagonal-dominant: no pivoting needed.
  for (int k2 = 0; k2 < NO; ++k2) {
    if (tid < NO) lds[OFF_FAC + tid] = lds[OFF_RG + tid*64 + k2];
    __syncthreads();
    const float pinv = 1.f / lds[OFF_FAC + k2];
    float oldv[8], vk[8];
    #pragma unroll
    for (int s2 = 0; s2 < 8; ++s2) {
      int idx = tid + s2*256;
      oldv[s2] = lds[OFF_RG + idx];
      vk[s2]   = lds[OFF_RG + k2*64 + (idx & 63)];
    }
    __syncthreads();
    #pragma unroll
    for (int s2 = 0; s2 < 8; ++s2) {
      int idx = tid + s2*256;
      int i = idx >> 6;
      lds[OFF_RG + idx] = (i == k2) ? (oldv[s2] * pinv)
                                    : (oldv[s2] - lds[OFF_FAC + i] * (vk[s2] * pinv));
    }
    __syncthreads();
  }
  // extract Rinv (32x32) into G scratch
  for (int idx = tid; idx < NO*NO; idx += 256) {
    int q = idx >> 5, p = idx & 31;
    lds[OFF_G + idx] = lds[OFF_RG + q*64 + NO + p];
  }
  __syncthreads();
  // RCt[k][q] = sum_p Rinv[q][p] * C[p][k]   (C[p][k] == Ct[k*32+p])
  for (int idx = tid; idx < NS*NO; idx += 256) {
    int k3 = idx >> 5, q = idx & 31;
    float a = 0.f;
    for (int p = 0; p < NO; ++p) a += lds[OFF_G + q*NO + p] * lds[OFF_CT + k3*NO + p];
    lds[OFF_RCT + k3*NO + q] = a;
  }

  // ================= persistent per-thread state =================
  // thread owns P/Q elements idx = tid + s*256  (i = 4s + w, j = lane)
  float Preg[16], Qreg[16];
  #pragma unroll
  for (int s = 0; s < 16; ++s) { Preg[s] = P0g[tid + s*256]; Qreg[s] = Qg[tid + s*256]; }
  float xr = 0.f;
  if (tid < NS) { xr = x0g[tid]; out[tid] = xr; }   // xs[0] = x0
  const float t0 = ts[0];
  const float h  = ts[1] - t0;

  float kPr[6][16];   // RK slopes for P, sans Q (Q folded analytically via row sums)
  float kxr[6];
  #pragma unroll
  for (int j = 0; j < 6; ++j) {
    kxr[j] = 0.f;
    #pragma unroll
    for (int s = 0; s < 16; ++s) kPr[j][s] = 0.f;
  }

  __syncthreads();

  // matmul register-tile mappings
  const int r0ap = (w << 4) + (((tid >> 4) & 3) << 2); // AP/M: 4 rows
  const int c0ap = (tid & 15) << 2;                    // AP/M: 4 cols
  const int r0g  = (tid >> 4) << 1;                    // G/RG: 2 rows
  const int c0g  = (tid & 15) << 2;                    // G/RG: 4 cols

  // ================= main scan =================
  for (int t = 0; t < TN - 1; ++t) {
    const float tcur = ts[t];
    #pragma unroll
    for (int st = 0; st < 6; ++st) {
      // ---- P1: stage combine (Pi, xi) + input interpolation ----
      {
        const float hc = h * CTAB[st];
        #pragma unroll
        for (int s = 0; s < 16; ++s) {
          float v = Preg[s];
          if (st > 0) {
            v += hc * Qreg[s];              // Q * (h * sum_j a_ij), row-sum = c_i
            #pragma unroll
            for (int j = 0; j < 5; ++j)
              if (ATAB[st][j] != 0.f) v += (h * ATAB[st][j]) * kPr[j][s];
          }
          lds[OFF_PIM + (s << 8) + tid] = v;
        }
        if (tid < NS) {
          float xi = xr;
          if (st > 0) {
            #pragma unroll
            for (int j = 0; j < 5; ++j)
              if (ATAB[st][j] != 0.f) xi += (h * ATAB[st][j]) * kxr[j];
          }
          lds[OFF_XV + tid] = xi;
          // linear interp on uniform grid, f32 math mirrors reference exactly
          const float sf = (tcur + CTAB[st] * h - t0) / h;
          int i0 = (int)floorf(sf);
          i0 = i0 < 0 ? 0 : (i0 > TN - 2 ? TN - 2 : i0);
          const float ww = sf - (float)i0;
          if (tid < NI) {
            lds[OFF_UV + tid] = us[i0*NI + tid] * (1.f - ww) + us[(i0+1)*NI + tid] * ww;
          } else if (tid >= 32) {
            const int q = tid - 32;
            lds[OFF_YV + q] = ys[i0*NO + q] * (1.f - ww) + ys[(i0+1)*NO + q] * ww;
          }
        }
      }
      __syncthreads();
      // ---- P2: G = C@Pi, RG = (Rinv C)@Pi (= K^T), Cx = C@xi ----
      {
        f4 aG0 = {0.f,0.f,0.f,0.f}, aG1 = aG0, aR0 = aG0, aR1 = aG0;
        for (int k = 0; k < NS; ++k) {
          const f2 cv = *(const f2*)&lds[OFF_CT  + k*NO + r0g];
          const f2 rv = *(const f2*)&lds[OFF_RCT + k*NO + r0g];
          const f4 pv = *(const f4*)&lds[OFF_PIM + k*NS + c0g];
          aG0 += cv.x * pv; aG1 += cv.y * pv;
          aR0 += rv.x * pv; aR1 += rv.y * pv;
        }
        *(f4*)&lds[OFF_G  + (r0g    )*NS + c0g] = aG0;
        *(f4*)&lds[OFF_G  + (r0g + 1)*NS + c0g] = aG1;
        *(f4*)&lds[OFF_RG + (r0g    )*NS + c0g] = aR0;
        *(f4*)&lds[OFF_RG + (r0g + 1)*NS + c0g] = aR1;
        if (tid < NO) {
          float a = 0.f;
          for (int k = 0; k < NS; ++k) a += lds[OFF_CT + k*NO + tid] * lds[OFF_XV + k];
          lds[OFF_CX + tid] = a;
        }
      }
      __syncthreads();
      // ---- P3: AP = A@Pi, M = K@G = RG^T@G ----
      {
        f4 acc0 = {0.f,0.f,0.f,0.f}, acc1 = acc0, acc2 = acc0, acc3 = acc0;
        for (int k = 0; k < NS; ++k) {
          const f4 av = *(const f4*)&lds[OFF_AT  + k*NS + r0ap];
          const f4 pv = *(const f4*)&lds[OFF_PIM + k*NS + c0ap];
          acc0 += av.x * pv; acc1 += av.y * pv;
          acc2 += av.z * pv; acc3 += av.w * pv;
        }
        #pragma unroll
        for (int b = 0; b < 4; ++b) {
          lds[OFF_AP + (r0ap + 0)*65 + c0ap + b] = acc0[b];
          lds[OFF_AP + (r0ap + 1)*65 + c0ap + b] = acc1[b];
          lds[OFF_AP + (r0ap + 2)*65 + c0ap + b] = acc2[b];
          lds[OFF_AP + (r0ap + 3)*65 + c0ap + b] = acc3[b];
        }
        f4 am0 = {0.f,0.f,0.f,0.f}, am1 = am0, am2 = am0, am3 = am0;
        for (int q = 0; q < NO; ++q) {
          const f4 kv = *(const f4*)&lds[OFF_RG + q*NS + r0ap];
          const f4 gv = *(const f4*)&lds[OFF_G  + q*NS + c0ap];
          am0 += kv.x * gv; am1 += kv.y * gv;
          am2 += kv.z * gv; am3 += kv.w * gv;
        }
        *(f4*)&lds[OFF_M + (r0ap + 0)*NS + c0ap] = am0;
        *(f4*)&lds[OFF_M + (r0ap + 1)*NS + c0ap] = am1;
        *(f4*)&lds[OFF_M + (r0ap + 2)*NS + c0ap] = am2;
        *(f4*)&lds[OFF_M + (r0ap + 3)*NS + c0ap] = am3;
      }
      __syncthreads();
      // ---- P4: slopes kP = AP + AP^T - M (Q folded), kx = rhs_x ----
      {
        #pragma unroll
        for (int s = 0; s < 16; ++s) {
          const int i = (s << 2) + w;
          kPr[st][s] = lds[OFF_AP + i*65 + lane] + lds[OFF_AP + lane*65 + i]
                     - lds[OFF_M + i*NS + lane];
        }
        if (tid < NS) {
          float a = 0.f;
          for (int k = 0; k < NS; ++k) a += lds[OFF_AT + k*NS + tid] * lds[OFF_XV + k];
          for (int m = 0; m < NI; ++m) a += lds[OFF_BT + m*NS + tid] * lds[OFF_UV + m];
          for (int q = 0; q < NO; ++q) a += lds[OFF_RG + q*NS + tid] * (lds[OFF_YV + q] - lds[OFF_CX + q]);
          kxr[st] = a;
        }
      }
      __syncthreads();
    } // stages

    // ---- 5th-order combine; sum(b) = 1 exactly -> + h*Q ----
    #pragma unroll
    for (int s = 0; s < 16; ++s)
      Preg[s] += h * (BW0*kPr[0][s] + BW2*kPr[2][s] + BW3*kPr[3][s]
                    + BW4*kPr[4][s] + BW5*kPr[5][s] + Qreg[s]);
    if (tid < NS) {
      xr += h * (BW0*kxr[0] + BW2*kxr[2] + BW3*kxr[3] + BW4*kxr[4] + BW5*kxr[5]);
      out[(t + 1)*NS + tid] = xr;
    }
  }
}

extern "C" void kernel_launch(void* const* d_in, const int* in_sizes, int n_in,
                              void* d_out, int out_size, void* d_ws, size_t ws_size,
                              hipStream_t stream) {
  (void)in_sizes; (void)n_in; (void)out_size; (void)d_ws; (void)ws_size;
  const float* ts  = (const float*)d_in[0];
  const float* ys  = (const float*)d_in[1];
  const float* us  = (const float*)d_in[2];
  const float* A   = (const float*)d_in[3];
  const float* B   = (const float*)d_in[4];
  const float* C   = (const float*)d_in[5];
  const float* x0  = (const float*)d_in[6];
  const float* P0  = (const float*)d_in[7];
  const float* Q   = (const float*)d_in[8];
  const float* R   = (const float*)d_in[9];
  float* out = (float*)d_out;

  const int shmem = LDS_FLOATS * (int)sizeof(float); // 103360 B > 64KB -> opt-in
  (void)hipFuncSetAttribute(reinterpret_cast<const void*>(kf_kernel),
                            hipFuncAttributeMaxDynamicSharedMemorySize, shmem);
  hipLaunchKernelGGL(kf_kernel, dim3(1), dim3(256), shmem, stream,
                     ts, ys, us, A, B, C, x0, P0, Q, R, out);
}

// Round 2
// 14484.779 us; speedup vs baseline: 5.6358x; 5.6358x over previous
//
#include <hip/hip_runtime.h>

typedef float f32x4 __attribute__((ext_vector_type(4)));
typedef short s16x8 __attribute__((ext_vector_type(8)));
typedef short s16x4 __attribute__((ext_vector_type(4)));

namespace kf {
constexpr int TN = 1024, NS = 64, NO = 32, NI = 16;
constexpr int PP = 72;  // u16 pitch for 64-col bf16 arrays (granule stride 9 -> conflict-free frags)
constexpr int PK = 40;  // u16 pitch for 32-col bf16 arrays (granule stride 5)
constexpr int PA = 65;  // f32 pitch for AP (transpose reads 2-way)

constexpr float ATAB[6][5] = {
  {0.f,0.f,0.f,0.f,0.f},
  {(float)(1.0/5.0),0.f,0.f,0.f,0.f},
  {(float)(3.0/40.0),(float)(9.0/40.0),0.f,0.f,0.f},
  {(float)(44.0/45.0),(float)(-56.0/15.0),(float)(32.0/9.0),0.f,0.f},
  {(float)(19372.0/6561.0),(float)(-25360.0/2187.0),(float)(64448.0/6561.0),(float)(-212.0/729.0),0.f},
  {(float)(9017.0/3168.0),(float)(-355.0/33.0),(float)(46732.0/5247.0),(float)(49.0/176.0),(float)(-5103.0/18656.0)},
};
constexpr float CTAB[6] = {0.f,(float)(1.0/5.0),(float)(3.0/10.0),(float)(4.0/5.0),(float)(8.0/9.0),1.f};
constexpr float BW0=(float)(35.0/384.0), BW2=(float)(500.0/1113.0), BW3=(float)(125.0/192.0),
                BW4=(float)(-2187.0/6784.0), BW5=(float)(11.0/84.0);

struct Sh {
  unsigned short Pib[64*PP];   // Pi bf16 (symmetric; serves as its own transpose)
  unsigned short Ab [64*PP];   // A row-major bf16
  unsigned short Cb [32*PP];   // C row-major bf16  (B^T array for GT = Pi@Ct)
  unsigned short RCb[32*PP];   // Rinv@C row-major bf16 (B^T array for KK = Pi@(Ct Rinv))
  unsigned short KKb[64*PK];   // KK = Pi Ct Rinv (gain), row-major bf16
  unsigned short GTb[64*PK];   // GT = Pi Ct = (C Pi)^T, row-major bf16
  float APf[64*PA];            // AP = A@Pi f32 (also init scratch: GJ aug / X16 ref)
  float Bf [64*16];            // B f32
  float XV[64], UV[16], YV[32], CXR[32], AX1[64], AX2[64], BU[64], FAC[32];
  int HYP;
};
} // namespace kf
using namespace kf;

__device__ inline float bf2f(unsigned short u){
  unsigned int x = ((unsigned int)u) << 16; return __builtin_bit_cast(float, x);
}
__device__ inline unsigned short f2bf(float f){
  unsigned int x = __builtin_bit_cast(unsigned int, f);
  unsigned int r = (x + 0x7fffu + ((x >> 16) & 1u)) >> 16;
  return (unsigned short)r;
}
// A/B-operand fragment loader for mfma_f32_16x16x32_bf16 from row-major bf16 array.
// hyp bit0: 0 = lane holds 8 contiguous k, 1 = two 4-contig k halves split at K/2.
__device__ inline s16x8 load_frag(const unsigned short* arr, int pitch, int row0, int k0, int hyp){
  const int l = (int)(threadIdx.x & 63), lc = l & 15, lg = l >> 4;
  const unsigned short* p = arr + (row0 + lc) * pitch + k0;
  if ((hyp & 1) == 0) {
    return *(const s16x8*)(p + lg * 8);
  } else {
    s16x4 a = *(const s16x4*)(p + lg * 4);
    s16x4 b = *(const s16x4*)(p + 16 + lg * 4);
    s16x8 r; r[0]=a[0]; r[1]=a[1]; r[2]=a[2]; r[3]=a[3]; r[4]=b[0]; r[5]=b[1]; r[6]=b[2]; r[7]=b[3];
    return r;
  }
}
__device__ inline f32x4 MF(s16x8 a, s16x8 b, f32x4 c, int hyp){
  if (hyp & 2) return __builtin_amdgcn_mfma_f32_16x16x32_bf16(b, a, c, 0, 0, 0);
  return __builtin_amdgcn_mfma_f32_16x16x32_bf16(a, b, c, 0, 0, 0);
}

__global__ __launch_bounds__(512, 2)
void kf_mfma(const float* __restrict__ ts, const float* __restrict__ ys,
             const float* __restrict__ us, const float* __restrict__ Ag,
             const float* __restrict__ Bg, const float* __restrict__ Cg,
             const float* __restrict__ x0g, const float* __restrict__ P0g,
             const float* __restrict__ Qg, const float* __restrict__ Rg,
             float* __restrict__ out)
{
  __shared__ Sh sh;
  const int tid = (int)threadIdx.x;
  const int wv = tid >> 6;        // wave 0..7
  const int l  = tid & 63;
  const int lc = l & 15, lg = l >> 4;

  // ===================== init: constants =====================
  for (int idx = tid; idx < 64*64; idx += 512) sh.Ab[(idx>>6)*PP + (idx&63)] = f2bf(Ag[idx]);
  for (int idx = tid; idx < 32*64; idx += 512) sh.Cb[(idx>>6)*PP + (idx&63)] = f2bf(Cg[idx]);
  for (int idx = tid; idx < 64*16; idx += 512) sh.Bf[idx] = Bg[idx];
  // Gauss-Jordan [R | I] in APf scratch (32 rows x 64)
  for (int idx = tid; idx < 32*64; idx += 512) {
    int r = idx >> 6, c = idx & 63;
    sh.APf[idx] = (c < 32) ? Rg[r*32 + c] : ((c - 32) == r ? 1.f : 0.f);
  }
  __syncthreads();
  for (int k2 = 0; k2 < 32; ++k2) {
    if (tid < 32) sh.FAC[tid] = sh.APf[tid*64 + k2];
    __syncthreads();
    const float pinv = 1.f / sh.FAC[k2];
    float oldv[4], vk[4];
    #pragma unroll
    for (int s = 0; s < 4; ++s) {
      int idx = tid + s*512;
      oldv[s] = sh.APf[idx];
      vk[s]   = sh.APf[k2*64 + (idx & 63)];
    }
    __syncthreads();
    #pragma unroll
    for (int s = 0; s < 4; ++s) {
      int idx = tid + s*512, i = idx >> 6;
      sh.APf[idx] = (i == k2) ? (oldv[s] * pinv) : (oldv[s] - sh.FAC[i] * (vk[s] * pinv));
    }
    __syncthreads();
  }
  // RC = Rinv @ C  -> RCb bf16
  for (int idx = tid; idx < 32*64; idx += 512) {
    int q = idx >> 6, k = idx & 63;
    float a = 0.f;
    for (int p = 0; p < 32; ++p) a += sh.APf[q*64 + 32 + p] * Cg[p*64 + k];
    sh.RCb[q*PP + k] = f2bf(a);
  }
  __syncthreads();
  // X16 reference for fragment-layout hypothesis test: X[r][c] = sum_{k<32} A[r][k]*A[16+c][k]
  if (tid < 256) {
    int r = tid >> 4, c = tid & 15;
    float a = 0.f;
    for (int k = 0; k < 32; ++k) a += bf2f(sh.Ab[r*PP + k]) * bf2f(sh.Ab[(16 + c)*PP + k]);
    sh.APf[3000 + tid] = a;
  }
  if (tid == 0) sh.HYP = -1;
  __syncthreads();
  for (int h = 0; h < 4; ++h) {
    if (wv == 0) {
      s16x8 af = load_frag(sh.Ab, PP, 0, 0, h);
      s16x8 bf = load_frag(sh.Ab, PP, 16, 0, h);
      f32x4 z = {0.f, 0.f, 0.f, 0.f};
      f32x4 d = MF(af, bf, z, h);
      int ok = 1;
      #pragma unroll
      for (int r = 0; r < 4; ++r) {
        int row = lg*4 + r, col = lc;
        float rf = sh.APf[3000 + row*16 + col];
        ok &= (fabsf(d[r] - rf) <= 1e-3f + 1e-2f * fabsf(rf)) ? 1 : 0;
      }
      if (__all(ok) && tid == 0) { if (sh.HYP < 0) sh.HYP = h; }
    }
    __syncthreads();
  }
  int sHyp = sh.HYP; if (sHyp < 0) sHyp = 0;

  // ===================== persistent state =====================
  const float tt0 = ts[0];
  const float h  = ts[1] - tt0;
  f32x4 Pfr[4], Qfr[4], kP[6][4], Macc[4];
  s16x8 aA[2], bRC[2][2], bCc[2][2];
  float xr = 0.f, kxr[6];
  #pragma unroll
  for (int j = 0; j < 6; ++j) kxr[j] = 0.f;
  f32x4 z4 = {0.f, 0.f, 0.f, 0.f};
  #pragma unroll
  for (int ct = 0; ct < 4; ++ct) { Pfr[ct] = z4; Qfr[ct] = z4; Macc[ct] = z4; }
  #pragma unroll
  for (int j = 0; j < 6; ++j)
    #pragma unroll
    for (int ct = 0; ct < 4; ++ct) kP[j][ct] = z4;

  if (wv < 4) {
    #pragma unroll
    for (int ct = 0; ct < 4; ++ct)
      #pragma unroll
      for (int r = 0; r < 4; ++r) {
        int row = 16*wv + 4*lg + r, col = 16*ct + lc;
        Pfr[ct][r] = P0g[row*64 + col];
        Qfr[ct][r] = Qg [row*64 + col];
      }
    aA[0] = load_frag(sh.Ab, PP, 16*wv, 0,  sHyp);
    aA[1] = load_frag(sh.Ab, PP, 16*wv, 32, sHyp);
  } else if (wv < 6) {
    #pragma unroll
    for (int ct = 0; ct < 2; ++ct)
      #pragma unroll
      for (int kb = 0; kb < 2; ++kb) bRC[ct][kb] = load_frag(sh.RCb, PP, 16*ct, 32*kb, sHyp);
  } else {
    #pragma unroll
    for (int ct = 0; ct < 2; ++ct)
      #pragma unroll
      for (int kb = 0; kb < 2; ++kb) bCc[ct][kb] = load_frag(sh.Cb, PP, 16*ct, 32*kb, sHyp);
  }
  if (wv == 4) { xr = x0g[l]; out[l] = xr; }
  __syncthreads();

  // ===================== main scan =====================
  for (int t = 0; t < TN - 1; ++t) {
    float tc = 0.f;
    if (wv == 5) tc = ts[t];
    #pragma unroll
    for (int st = 0; st < 6; ++st) {
      // ---- phase A: slopes of prev stage + stage combine + stage inputs ----
      if (wv < 4) {
        const int ps = (st == 0) ? 5 : st - 1;
        if (st > 0 || t > 0) {
          #pragma unroll
          for (int ct = 0; ct < 4; ++ct)
            #pragma unroll
            for (int r = 0; r < 4; ++r) {
              int row = 16*wv + 4*lg + r, col = 16*ct + lc;
              kP[ps][ct][r] = sh.APf[row*PA + col] + sh.APf[col*PA + row] - Macc[ct][r];
            }
        }
        #pragma unroll
        for (int ct = 0; ct < 4; ++ct)
          #pragma unroll
          for (int r = 0; r < 4; ++r) {
            float v;
            if (st == 0) {
              if (t > 0)
                Pfr[ct][r] += h * (BW0*kP[0][ct][r] + BW2*kP[2][ct][r] + BW3*kP[3][ct][r]
                                 + BW4*kP[4][ct][r] + BW5*kP[5][ct][r] + Qfr[ct][r]);
              v = Pfr[ct][r];
            } else {
              v = Pfr[ct][r] + (h * CTAB[st]) * Qfr[ct][r];
              #pragma unroll
              for (int j = 0; j < 5; ++j)
                if (ATAB[st][j] != 0.f) v += (h * ATAB[st][j]) * kP[j][ct][r];
            }
            sh.Pib[(16*wv + 4*lg + r)*PP + 16*ct + lc] = f2bf(v);
          }
      } else if (wv == 4) {
        if (st > 0 || t > 0) {
          const int ps = (st == 0) ? 5 : st - 1;
          float kx = sh.AX1[l] + sh.AX2[l] + sh.BU[l];
          for (int q = 0; q < 32; ++q) kx += bf2f(sh.KKb[l*PK + q]) * sh.CXR[q];
          kxr[ps] = kx;
        }
        float xi;
        if (st == 0) {
          if (t > 0) {
            xr += h * (BW0*kxr[0] + BW2*kxr[2] + BW3*kxr[3] + BW4*kxr[4] + BW5*kxr[5]);
            out[t*64 + l] = xr;
          }
          xi = xr;
        } else {
          xi = xr;
          #pragma unroll
          for (int j = 0; j < 5; ++j)
            if (ATAB[st][j] != 0.f) xi += (h * ATAB[st][j]) * kxr[j];
        }
        sh.XV[l] = xi;
      } else if (wv == 5) {
        if (l < 16 || l >= 32) {
          float te = tc + CTAB[st] * h;
          float sf = (te - tt0) / h;
          int i0 = (int)floorf(sf);
          i0 = i0 < 0 ? 0 : (i0 > TN - 2 ? TN - 2 : i0);
          float wf = sf - (float)i0;
          if (l < 16) sh.UV[l] = us[i0*NI + l] * (1.f - wf) + us[(i0+1)*NI + l] * wf;
          else { int q = l - 32; sh.YV[q] = ys[i0*NO + q] * (1.f - wf) + ys[(i0+1)*NO + q] * wf; }
        }
      }
      __syncthreads();
      // ---- phase B: AP = A@Pi (w0-3) | KK = Pi@RCt (w4-5) | GT = Pi@Ct (w6-7) ----
      if (wv < 4) {
        f32x4 ap[4];
        #pragma unroll
        for (int ct = 0; ct < 4; ++ct) {
          ap[ct] = z4;
          #pragma unroll
          for (int kb = 0; kb < 2; ++kb) {
            s16x8 bP = load_frag(sh.Pib, PP, 16*ct, 32*kb, sHyp);
            ap[ct] = MF(aA[kb], bP, ap[ct], sHyp);
          }
        }
        #pragma unroll
        for (int ct = 0; ct < 4; ++ct)
          #pragma unroll
          for (int r = 0; r < 4; ++r)
            sh.APf[(16*wv + 4*lg + r)*PA + 16*ct + lc] = ap[ct][r];
      } else {
        const int half = wv & 1;
        f32x4 acc2[2][2];
        acc2[0][0] = z4; acc2[0][1] = z4; acc2[1][0] = z4; acc2[1][1] = z4;
        #pragma unroll
        for (int rt = 0; rt < 2; ++rt)
          #pragma unroll
          for (int kb = 0; kb < 2; ++kb) {
            s16x8 aPi = load_frag(sh.Pib, PP, 32*half + 16*rt, 32*kb, sHyp);
            #pragma unroll
            for (int ct = 0; ct < 2; ++ct) {
              s16x8 bc = (wv < 6) ? bRC[ct][kb] : bCc[ct][kb];
              acc2[rt][ct] = MF(aPi, bc, acc2[rt][ct], sHyp);
            }
          }
        unsigned short* dst = (wv < 6) ? sh.KKb : sh.GTb;
        #pragma unroll
        for (int rt = 0; rt < 2; ++rt)
          #pragma unroll
          for (int ct = 0; ct < 2; ++ct)
            #pragma unroll
            for (int r = 0; r < 4; ++r)
              dst[(32*half + 16*rt + 4*lg + r)*PK + 16*ct + lc] = f2bf(acc2[rt][ct][r]);
      }
      __syncthreads();
      // ---- phase C: M = KK@G (w0-3) | Cx (w5) | Bu+Ax halves (w6,7) ----
      if (wv < 4) {
        s16x8 am = load_frag(sh.KKb, PK, 16*wv, 0, sHyp);
        #pragma unroll
        for (int ct = 0; ct < 4; ++ct) {
          s16x8 bg = load_frag(sh.GTb, PK, 16*ct, 0, sHyp);
          Macc[ct] = MF(am, bg, z4, sHyp);
        }
      } else if (wv == 5) {
        int q = l >> 1, kh = (l & 1) * 32;
        float cx = 0.f;
        for (int k = 0; k < 32; ++k) cx += bf2f(sh.Cb[q*PP + kh + k]) * sh.XV[kh + k];
        cx += __shfl_xor(cx, 1);
        if ((l & 1) == 0) sh.CXR[q] = sh.YV[q] - cx;
      } else if (wv == 6) {
        float bu = 0.f;
        for (int m = 0; m < 16; ++m) bu += sh.Bf[l*16 + m] * sh.UV[m];
        sh.BU[l] = bu;
        float a1 = 0.f;
        for (int k = 0; k < 32; ++k) a1 += bf2f(sh.Ab[l*PP + k]) * sh.XV[k];
        sh.AX1[l] = a1;
      } else if (wv == 7) {
        float a2 = 0.f;
        for (int k = 32; k < 64; ++k) a2 += bf2f(sh.Ab[l*PP + k]) * sh.XV[k];
        sh.AX2[l] = a2;
      }
      __syncthreads();
    } // stages
  } // t

  // tail: last slope + final x combine for t = TN-1
  if (wv == 4) {
    float kx = sh.AX1[l] + sh.AX2[l] + sh.BU[l];
    for (int q = 0; q < 32; ++q) kx += bf2f(sh.KKb[l*PK + q]) * sh.CXR[q];
    kxr[5] = kx;
    xr += h * (BW0*kxr[0] + BW2*kxr[2] + BW3*kxr[3] + BW4*kxr[4] + BW5*kxr[5]);
    out[(TN - 1)*64 + l] = xr;
  }
}

extern "C" void kernel_launch(void* const* d_in, const int* in_sizes, int n_in,
                              void* d_out, int out_size, void* d_ws, size_t ws_size,
                              hipStream_t stream) {
  (void)in_sizes; (void)n_in; (void)out_size; (void)d_ws; (void)ws_size;
  const float* ts  = (const float*)d_in[0];
  const float* ys  = (const float*)d_in[1];
  const float* us  = (const float*)d_in[2];
  const float* A   = (const float*)d_in[3];
  const float* B   = (const float*)d_in[4];
  const float* C   = (const float*)d_in[5];
  const float* x0  = (const float*)d_in[6];
  const float* P0  = (const float*)d_in[7];
  const float* Q   = (const float*)d_in[8];
  const float* R   = (const float*)d_in[9];
  hipLaunchKernelGGL(kf_mfma, dim3(1), dim3(512), 0, stream,
                     ts, ys, us, A, B, C, x0, P0, Q, R, (float*)d_out);
}